// Round 9
// baseline (199.827 us; speedup 1.0000x reference)
//
#include <hip/hip_runtime.h>
#include <cstdint>
#include <cstddef>

// DigitCapsules routing: B=256, R=1152, C=10, IC=8, OC=16, 3 iters.
// R9 (7 launches): R8 structure, passes rebuilt for latency hiding:
//   caps_u: u[b][c][r][o] bf16 (94 MB). R6-proven shape (64 VGPR, no spill).
//   3x { caps_pass(NSPLIT=9: 2304 blocks, TWO r per thread loaded as ONE
//        20-deep burst; launch_bounds(256,4) -> 16 waves/CU resident with
//        ~320 loads in flight/CU; epilogue shuffle-reduce trimmed 160->80 ops
//        by stopping at 4-lane groups and finishing in LDS);
//        caps_reduce: sum 9 partials + squash + vsum/out }
// Logits linear in v: b_t = u.(v1+..+v_{t-1}) -> running vsum, 1 pass/iter.
// R7/R8 lesson: pass time = f(resident waves x outstanding loads) with DS
// kept under the memory floor; NSPLIT=2 starved occupancy, NSPLIT=18
// DS-flooded. NSPLIT=9 + burst-20 + lean epilogue hits all three.
#define NB 256
#define NR 1152
#define NC 10
#define NI 8
#define NO 16
#define NSPLIT 9
#define RSPL 128     // r per split: 2 r per thread (rl and rl+64)

static __device__ __forceinline__ uint32_t bf16_pack2(float lo, float hi) {
    uint32_t vl = __float_as_uint(lo);
    vl = vl + 0x7FFFu + ((vl >> 16) & 1u);
    uint32_t vh = __float_as_uint(hi);
    vh = vh + 0x7FFFu + ((vh >> 16) & 1u);
    return (vl >> 16) | (vh & 0xFFFF0000u);
}

// -------------------------------------------------------------------------
// caps_u: grid 2304 = 144 r-chunks(8 r) x 16 b-groups(16 b). 320 thr:
// t = c*32 + rl*4 + oq. W[r][c][i][oq*4..+3] = 8 float4 in regs. UNCHANGED.
__global__ __launch_bounds__(320) void caps_u_kernel(
    const float* __restrict__ x, const float* __restrict__ W,
    uint32_t* __restrict__ u)
{
    const int t  = threadIdx.x;
    const int c  = t >> 5;             // 0..9
    const int rl = (t & 31) >> 2;      // 0..7
    const int oq = t & 3;              // 0..3
    const int rc = blockIdx.x >> 4;    // 0..143
    const int bg = blockIdx.x & 15;    // 0..15
    const int b0 = bg * 16;
    const int r  = rc * 8 + rl;

    __shared__ float xs[16][8][8];     // 4 KB

    if (t < 256) {                     // 256 float4 = x[b0..+16)[rc*8..+8)[8]
        const int bi = t >> 4, rem = t & 15;
        const int rr = rem >> 1, hf = rem & 1;
        *(float4*)&xs[bi][rr][hf * 4] =
            *(const float4*)(x + ((size_t)(b0 + bi) * NR + rc * 8 + rr) * 8 + hf * 4);
    }

    const float* wb = W + ((size_t)r * NC + c) * (NI * NO) + oq * 4;
    float4 wf[8];
#pragma unroll
    for (int i = 0; i < 8; ++i) wf[i] = *(const float4*)(wb + i * NO);

    __syncthreads();

    for (int bi = 0; bi < 16; ++bi) {
        const float4 xv4a = *(const float4*)&xs[bi][rl][0];   // ds_read_b128
        const float4 xv4b = *(const float4*)&xs[bi][rl][4];
        const float xr[8] = {xv4a.x, xv4a.y, xv4a.z, xv4a.w,
                             xv4b.x, xv4b.y, xv4b.z, xv4b.w};
        float ax = 0.f, ay = 0.f, az = 0.f, aw = 0.f;
#pragma unroll
        for (int i = 0; i < 8; ++i) {
            const float xv = xr[i];
            ax = fmaf(xv, wf[i].x, ax); ay = fmaf(xv, wf[i].y, ay);
            az = fmaf(xv, wf[i].z, az); aw = fmaf(xv, wf[i].w, aw);
        }
        uint2 s;
        s.x = bf16_pack2(ax, ay);
        s.y = bf16_pack2(az, aw);
        *(uint2*)(u + (((size_t)(b0 + bi) * NC + c) * NR + r) * 8 + oq * 2) = s;
    }
}

// -------------------------------------------------------------------------
// Routing pass: block = (b, sp), 256 thr = 64 rl x 4 oq; TWO r per thread
// (r, r+64) loaded as one 20-deep burst for MLP. mode 0: uniform (0.1 at
// epilogue). mode 1: cc = softmax_c(u.vsum). Partials -> part[sp][b][160].
__global__ __launch_bounds__(256, 4) void caps_pass_kernel(
    const uint32_t* __restrict__ u, const float* __restrict__ vsum,
    float* __restrict__ part, const int mode)
{
    const int b  = blockIdx.x / NSPLIT;
    const int sp = blockIdx.x % NSPLIT;
    const int t  = threadIdx.x;
    const int oq = t & 3;
    const int rl = t >> 2;    // 0..63
    const int r0 = sp * RSPL + rl;

    __shared__ float vss[160];
    __shared__ float sred[16][164];   // +4 pad: g-stride 164%32=4 -> no conflict

    if (mode != 0 && t < 160) vss[t] = vsum[(size_t)b * 160 + t];
    __syncthreads();

    const uint2* ub = (const uint2*)u + (size_t)b * NC * NR * 4 + oq;

    // ---- one 20-deep load burst (both r's, all c) ----
    uint2 q[2][10];
#pragma unroll
    for (int c = 0; c < 10; ++c) q[0][c] = ub[((size_t)c * NR + r0) * 4];
#pragma unroll
    for (int c = 0; c < 10; ++c) q[1][c] = ub[((size_t)c * NR + r0 + 64) * 4];

    float acc[10][4];
#pragma unroll
    for (int c = 0; c < 10; ++c)
#pragma unroll
        for (int j = 0; j < 4; ++j) acc[c][j] = 0.f;

#pragma unroll
    for (int h = 0; h < 2; ++h) {
        if (mode != 0) {
            float lg[10];
#pragma unroll
            for (int c = 0; c < 10; ++c) {
                const float4 vq = *(const float4*)&vss[c * 16 + oq * 4];
                float d = __uint_as_float(q[h][c].x << 16) * vq.x;
                d = fmaf(__uint_as_float(q[h][c].x & 0xFFFF0000u), vq.y, d);
                d = fmaf(__uint_as_float(q[h][c].y << 16),         vq.z, d);
                d = fmaf(__uint_as_float(q[h][c].y & 0xFFFF0000u), vq.w, d);
                lg[c] = d;
            }
#pragma unroll
            for (int c = 0; c < 10; ++c) {    // finish o-dot over 4 oq lanes
                lg[c] += __shfl_xor(lg[c], 1);
                lg[c] += __shfl_xor(lg[c], 2);
            }
            float m = lg[0];
#pragma unroll
            for (int c = 1; c < 10; ++c) m = fmaxf(m, lg[c]);
            float wgt[10], ssum = 0.f;
#pragma unroll
            for (int c = 0; c < 10; ++c) { wgt[c] = __expf(lg[c] - m); ssum += wgt[c]; }
            const float inv = 1.f / ssum;
#pragma unroll
            for (int c = 0; c < 10; ++c) {
                const float wv = wgt[c] * inv;
                acc[c][0] = fmaf(wv, __uint_as_float(q[h][c].x << 16),         acc[c][0]);
                acc[c][1] = fmaf(wv, __uint_as_float(q[h][c].x & 0xFFFF0000u), acc[c][1]);
                acc[c][2] = fmaf(wv, __uint_as_float(q[h][c].y << 16),         acc[c][2]);
                acc[c][3] = fmaf(wv, __uint_as_float(q[h][c].y & 0xFFFF0000u), acc[c][3]);
            }
        } else {
#pragma unroll
            for (int c = 0; c < 10; ++c) {
                acc[c][0] += __uint_as_float(q[h][c].x << 16);
                acc[c][1] += __uint_as_float(q[h][c].x & 0xFFFF0000u);
                acc[c][2] += __uint_as_float(q[h][c].y << 16);
                acc[c][3] += __uint_as_float(q[h][c].y & 0xFFFF0000u);
            }
        }
    }

    // lean epilogue: reduce only rl bits 0,1 (xor 4,8) -> 4 groups per wave
#pragma unroll
    for (int off = 4; off <= 8; off <<= 1)
#pragma unroll
        for (int c = 0; c < 10; ++c)
#pragma unroll
            for (int j = 0; j < 4; ++j) acc[c][j] += __shfl_xor(acc[c][j], off);

    const int lane = t & 63;
    const int wv   = t >> 6;
    const int g    = lane >> 4;           // rl-group 0..3
    if (((lane >> 2) & 3) == 0) {         // one lane-quad per group
#pragma unroll
        for (int c = 0; c < 10; ++c)
#pragma unroll
            for (int j = 0; j < 4; ++j)
                sred[wv * 4 + g][c * 16 + oq * 4 + j] = acc[c][j];
    }
    __syncthreads();

    if (t < 160) {
        float s = 0.f;
#pragma unroll
        for (int w = 0; w < 16; ++w) s += sred[w][t];
        if (mode == 0) s *= 0.1f;
        part[((size_t)sp * NB + b) * 160 + t] = s;
    }
}

// -------------------------------------------------------------------------
// sum NSPLIT partials + squash. grid=256 (b), 192 thr (160 active).
// mode 0: vsum = v ; 1: vsum += v ; 2: out = v
__global__ __launch_bounds__(192) void caps_reduce_kernel(
    const float* __restrict__ part, float* __restrict__ vsum,
    float* __restrict__ out, const int mode)
{
    const int b = blockIdx.x;
    const int t = threadIdx.x;
    if (t >= 160) return;
    float s = 0.f;
#pragma unroll
    for (int sp = 0; sp < NSPLIT; ++sp)
        s += part[((size_t)sp * NB + b) * 160 + t];
    float n2 = s * s;                 // squash over o (t & 15)
    n2 += __shfl_xor(n2, 1);
    n2 += __shfl_xor(n2, 2);
    n2 += __shfl_xor(n2, 4);
    n2 += __shfl_xor(n2, 8);
    const float nrm   = sqrtf(n2);
    const float scale = n2 / (1.f + n2) / (nrm + 1e-8f);
    const float v = scale * s;
    if (mode == 0)      vsum[(size_t)b * 160 + t] = v;
    else if (mode == 1) vsum[(size_t)b * 160 + t] += v;
    else                out[(size_t)b * 160 + t] = v;
}

// -------------------------------------------------------------------------
extern "C" void kernel_launch(void* const* d_in, const int* in_sizes, int n_in,
                              void* d_out, int out_size, void* d_ws, size_t ws_size,
                              hipStream_t stream) {
    const float* x = (const float*)d_in[0];   // [256,1152,8]
    const float* W = (const float*)d_in[1];   // [1,1152,10,8,16]
    float* out = (float*)d_out;               // [256,10,16]

    // ws: u bf16 94,371,840 | part 9*256*160*4 = 1,474,560 | vsum 163,840
    uint8_t*  ws  = (uint8_t*)d_ws;
    uint32_t* u   = (uint32_t*)ws;
    float*    prt = (float*)(ws + 94371840u);
    float*    vsm = (float*)(ws + 94371840u + 1474560u);

    caps_u_kernel     <<<2304, 320, 0, stream>>>(x, W, u);
    caps_pass_kernel  <<<NB * NSPLIT, 256, 0, stream>>>(u, vsm, prt, 0);
    caps_reduce_kernel<<<NB, 192, 0, stream>>>(prt, vsm, nullptr, 0);
    caps_pass_kernel  <<<NB * NSPLIT, 256, 0, stream>>>(u, vsm, prt, 1);
    caps_reduce_kernel<<<NB, 192, 0, stream>>>(prt, vsm, nullptr, 1);
    caps_pass_kernel  <<<NB * NSPLIT, 256, 0, stream>>>(u, vsm, prt, 1);
    caps_reduce_kernel<<<NB, 192, 0, stream>>>(prt, nullptr, out, 2);
}

// Round 10
// 169.993 us; speedup vs baseline: 1.1755x; 1.1755x over previous
//
#include <hip/hip_runtime.h>
#include <cstdint>
#include <cstddef>

// DigitCapsules routing: B=256, R=1152, C=10, IC=8, OC=16, 3 iters.
// R10 (7 launches): 16-byte-per-lane memory ops everywhere on the u stream.
//   caps_u: thread=(c,rl,oh): W=64 regs (cap 256 - no spill), uint4 stores.
//   3x { caps_pass(NSPLIT=3, 768 blocks, 3 sweeps of 128 r): uint4 u-loads
//        (16B/lane), 10-deep bursts, acc[10][8], unpack-twice to hold VGPR
//        ~155; epilogue xor2+xor4 -> 32 LDS rows -> t<160;
//        caps_reduce: sum 3 partials + squash + vsum/out }
// Logits linear in v: b_t = u.(v1+..+v_{t-1}) -> running vsum, 1 pass/iter.
// R9 lesson: never cap VGPR below ~1.5x the live set. R10 hypothesis: the
// stubborn 2.6 TB/s pass BW = 8B/lane loads halving bytes-in-flight.
#define NB 256
#define NR 1152
#define NC 10
#define NI 8
#define NO 16
#define NSPLIT 3
#define RSPL 384     // r per split: 3 sweeps x 128 rl

static __device__ __forceinline__ uint32_t bf16_pack2(float lo, float hi) {
    uint32_t vl = __float_as_uint(lo);
    vl = vl + 0x7FFFu + ((vl >> 16) & 1u);
    uint32_t vh = __float_as_uint(hi);
    vh = vh + 0x7FFFu + ((vh >> 16) & 1u);
    return (vl >> 16) | (vh & 0xFFFF0000u);
}

// -------------------------------------------------------------------------
// caps_u: grid 1152 = 72 r-chunks(16 r) x 16 b-groups(16 b). 320 thr:
// t = c*32 + rl*2 + oh. W[r][c][i][oh*8..+7] = 16 float4 in regs (64 VGPR,
// cap 256 via (320,2) -> safe). Stores uint4 (16 B/lane), 512 B contiguous
// per c-group per wave.
__global__ __launch_bounds__(320, 2) void caps_u_kernel(
    const float* __restrict__ x, const float* __restrict__ W,
    uint32_t* __restrict__ u)
{
    const int t  = threadIdx.x;
    const int c  = t >> 5;             // 0..9
    const int rl = (t & 31) >> 1;      // 0..15
    const int oh = t & 1;              // o-half
    const int rc = blockIdx.x >> 4;    // 0..71
    const int bg = blockIdx.x & 15;    // 0..15
    const int b0 = bg * 16;
    const int r  = rc * 16 + rl;

    __shared__ float xs[16][16][12];   // 12-dword stride: 16B-aligned, <=2-way

    for (int k = t; k < 512; k += 320) {   // x[b0..+16)[rc*16..+16)[8]
        const int bi = k >> 5, rem = k & 31;
        const int rr = rem >> 1, hf = rem & 1;
        *(float4*)&xs[bi][rr][hf * 4] =
            *(const float4*)(x + ((size_t)(b0 + bi) * NR + rc * 16 + rr) * 8 + hf * 4);
    }

    const float* wb = W + ((size_t)r * NC + c) * (NI * NO) + oh * 8;
    float4 wf[16];
#pragma unroll
    for (int i = 0; i < 8; ++i) {
        wf[i * 2 + 0] = *(const float4*)(wb + i * NO);
        wf[i * 2 + 1] = *(const float4*)(wb + i * NO + 4);
    }
    __syncthreads();

    for (int bi = 0; bi < 16; ++bi) {
        const float4 xa = *(const float4*)&xs[bi][rl][0];   // ds_read_b128
        const float4 xb = *(const float4*)&xs[bi][rl][4];
        const float xr[8] = {xa.x, xa.y, xa.z, xa.w, xb.x, xb.y, xb.z, xb.w};
        float a[8];
#pragma unroll
        for (int j = 0; j < 8; ++j) a[j] = 0.f;
#pragma unroll
        for (int i = 0; i < 8; ++i) {
            const float xv = xr[i];
            const float4 w0 = wf[i * 2 + 0], w1 = wf[i * 2 + 1];
            a[0] = fmaf(xv, w0.x, a[0]); a[1] = fmaf(xv, w0.y, a[1]);
            a[2] = fmaf(xv, w0.z, a[2]); a[3] = fmaf(xv, w0.w, a[3]);
            a[4] = fmaf(xv, w1.x, a[4]); a[5] = fmaf(xv, w1.y, a[5]);
            a[6] = fmaf(xv, w1.z, a[6]); a[7] = fmaf(xv, w1.w, a[7]);
        }
        uint4 s;
        s.x = bf16_pack2(a[0], a[1]); s.y = bf16_pack2(a[2], a[3]);
        s.z = bf16_pack2(a[4], a[5]); s.w = bf16_pack2(a[6], a[7]);
        *(uint4*)(u + (((size_t)(b0 + bi) * NC + c) * NR + r) * 8 + oh * 4) = s;
    }
}

// -------------------------------------------------------------------------
// Routing pass: block = (b, sp), 256 thr = 128 rl x 2 oh; 3 sweeps of 128 r.
// Per (c,r): ONE uint4 load (16 B/lane, 1 KB contiguous per wave-instr).
// mode 0: uniform (0.1 at epilogue). mode 1: cc = softmax_c(u.vsum).
// Partials -> part[sp][b][160]. No atomics.
__global__ __launch_bounds__(256, 2) void caps_pass_kernel(
    const uint32_t* __restrict__ u, const float* __restrict__ vsum,
    float* __restrict__ part, const int mode)
{
    const int b  = blockIdx.x / NSPLIT;
    const int sp = blockIdx.x % NSPLIT;
    const int t  = threadIdx.x;
    const int oh = t & 1;
    const int rl = t >> 1;    // 0..127

    __shared__ float vss[160];
    __shared__ float sred[32][164];   // 32 rows, stride 164 (16B-aligned)

    if (mode != 0 && t < 160) vss[t] = vsum[(size_t)b * 160 + t];
    __syncthreads();

    float acc[10][8];
#pragma unroll
    for (int c = 0; c < 10; ++c)
#pragma unroll
        for (int j = 0; j < 8; ++j) acc[c][j] = 0.f;

    // uint4 units: row (b,c,r) = 2 uint4; this thread's half = +oh
    const uint4* ub = (const uint4*)u + (size_t)b * NC * NR * 2 + oh;

    for (int k = 0; k < 3; ++k) {
        const int r = sp * RSPL + k * 128 + rl;
        uint4 q[10];
#pragma unroll
        for (int c = 0; c < 10; ++c) q[c] = ub[((size_t)c * NR + r) * 2];

        float wgt[10];
        if (mode != 0) {
            float lg[10];
#pragma unroll
            for (int c = 0; c < 10; ++c) {
                const float4 v0 = *(const float4*)&vss[c * 16 + oh * 8];
                const float4 v1 = *(const float4*)&vss[c * 16 + oh * 8 + 4];
                float d;
                d = __uint_as_float(q[c].x << 16)                 * v0.x;
                d = fmaf(__uint_as_float(q[c].x & 0xFFFF0000u), v0.y, d);
                d = fmaf(__uint_as_float(q[c].y << 16),         v0.z, d);
                d = fmaf(__uint_as_float(q[c].y & 0xFFFF0000u), v0.w, d);
                d = fmaf(__uint_as_float(q[c].z << 16),         v1.x, d);
                d = fmaf(__uint_as_float(q[c].z & 0xFFFF0000u), v1.y, d);
                d = fmaf(__uint_as_float(q[c].w << 16),         v1.z, d);
                d = fmaf(__uint_as_float(q[c].w & 0xFFFF0000u), v1.w, d);
                lg[c] = d;
            }
#pragma unroll
            for (int c = 0; c < 10; ++c)      // combine the two o-halves
                lg[c] += __shfl_xor(lg[c], 1);
            float m = lg[0];
#pragma unroll
            for (int c = 1; c < 10; ++c) m = fmaxf(m, lg[c]);
            float ssum = 0.f;
#pragma unroll
            for (int c = 0; c < 10; ++c) { wgt[c] = __expf(lg[c] - m); ssum += wgt[c]; }
            const float inv = 1.f / ssum;
#pragma unroll
            for (int c = 0; c < 10; ++c) wgt[c] *= inv;
        } else {
#pragma unroll
            for (int c = 0; c < 10; ++c) wgt[c] = 1.f;   // 0.1 at epilogue
        }
#pragma unroll
        for (int c = 0; c < 10; ++c) {
            const float wv = wgt[c];
            acc[c][0] = fmaf(wv, __uint_as_float(q[c].x << 16),         acc[c][0]);
            acc[c][1] = fmaf(wv, __uint_as_float(q[c].x & 0xFFFF0000u), acc[c][1]);
            acc[c][2] = fmaf(wv, __uint_as_float(q[c].y << 16),         acc[c][2]);
            acc[c][3] = fmaf(wv, __uint_as_float(q[c].y & 0xFFFF0000u), acc[c][3]);
            acc[c][4] = fmaf(wv, __uint_as_float(q[c].z << 16),         acc[c][4]);
            acc[c][5] = fmaf(wv, __uint_as_float(q[c].z & 0xFFFF0000u), acc[c][5]);
            acc[c][6] = fmaf(wv, __uint_as_float(q[c].w << 16),         acc[c][6]);
            acc[c][7] = fmaf(wv, __uint_as_float(q[c].w & 0xFFFF0000u), acc[c][7]);
        }
    }

    // epilogue: reduce rl bits 0,1 in-wave (lane = rl*2+oh -> xor 2, 4)
#pragma unroll
    for (int off = 2; off <= 4; off <<= 1)
#pragma unroll
        for (int c = 0; c < 10; ++c)
#pragma unroll
            for (int j = 0; j < 8; ++j) acc[c][j] += __shfl_xor(acc[c][j], off);

    const int lane = t & 63;
    const int wv   = t >> 6;
    if (((lane >> 1) & 3) == 0) {      // rl_local % 4 == 0: 16 lanes/wave
        const int g   = lane >> 3;     // 0..7
        const int row = wv * 8 + g;
#pragma unroll
        for (int c = 0; c < 10; ++c) {
            *(float4*)&sred[row][c * 16 + oh * 8]     = *(float4*)&acc[c][0];
            *(float4*)&sred[row][c * 16 + oh * 8 + 4] = *(float4*)&acc[c][4];
        }
    }
    __syncthreads();

    if (t < 160) {
        float s = 0.f;
#pragma unroll
        for (int w = 0; w < 32; ++w) s += sred[w][t];
        if (mode == 0) s *= 0.1f;
        part[((size_t)sp * NB + b) * 160 + t] = s;
    }
}

// -------------------------------------------------------------------------
// sum NSPLIT partials + squash. grid=256 (b), 192 thr (160 active).
// mode 0: vsum = v ; 1: vsum += v ; 2: out = v
__global__ __launch_bounds__(192) void caps_reduce_kernel(
    const float* __restrict__ part, float* __restrict__ vsum,
    float* __restrict__ out, const int mode)
{
    const int b = blockIdx.x;
    const int t = threadIdx.x;
    if (t >= 160) return;
    float s = 0.f;
#pragma unroll
    for (int sp = 0; sp < NSPLIT; ++sp)
        s += part[((size_t)sp * NB + b) * 160 + t];
    float n2 = s * s;                 // squash over o (t & 15)
    n2 += __shfl_xor(n2, 1);
    n2 += __shfl_xor(n2, 2);
    n2 += __shfl_xor(n2, 4);
    n2 += __shfl_xor(n2, 8);
    const float nrm   = sqrtf(n2);
    const float scale = n2 / (1.f + n2) / (nrm + 1e-8f);
    const float v = scale * s;
    if (mode == 0)      vsum[(size_t)b * 160 + t] = v;
    else if (mode == 1) vsum[(size_t)b * 160 + t] += v;
    else                out[(size_t)b * 160 + t] = v;
}

// -------------------------------------------------------------------------
extern "C" void kernel_launch(void* const* d_in, const int* in_sizes, int n_in,
                              void* d_out, int out_size, void* d_ws, size_t ws_size,
                              hipStream_t stream) {
    const float* x = (const float*)d_in[0];   // [256,1152,8]
    const float* W = (const float*)d_in[1];   // [1,1152,10,8,16]
    float* out = (float*)d_out;               // [256,10,16]

    // ws: u bf16 94,371,840 | part 3*256*160*4 = 491,520 | vsum 163,840
    uint8_t*  ws  = (uint8_t*)d_ws;
    uint32_t* u   = (uint32_t*)ws;
    float*    prt = (float*)(ws + 94371840u);
    float*    vsm = (float*)(ws + 94371840u + 491520u);

    caps_u_kernel     <<<1152, 320, 0, stream>>>(x, W, u);
    caps_pass_kernel  <<<NB * NSPLIT, 256, 0, stream>>>(u, vsm, prt, 0);
    caps_reduce_kernel<<<NB, 192, 0, stream>>>(prt, vsm, nullptr, 0);
    caps_pass_kernel  <<<NB * NSPLIT, 256, 0, stream>>>(u, vsm, prt, 1);
    caps_reduce_kernel<<<NB, 192, 0, stream>>>(prt, vsm, nullptr, 1);
    caps_pass_kernel  <<<NB * NSPLIT, 256, 0, stream>>>(u, vsm, prt, 1);
    caps_reduce_kernel<<<NB, 192, 0, stream>>>(prt, nullptr, out, 2);
}

// Round 11
// 166.042 us; speedup vs baseline: 1.2035x; 1.0238x over previous
//
#include <hip/hip_runtime.h>
#include <cstdint>
#include <cstddef>

// DigitCapsules routing: B=256, R=1152, C=10, IC=8, OC=16, 3 iters.
// R11 (6 launches):
//   caps_u_s1: u[b][c][r][o] bf16 (94 MB) + FUSED pass-0 partial (s1 =
//     0.1*sum_r u needs no softmax -> reduce over the block's 8 r via 12
//     shuffles/bi while u is in regs; fp32-exact). Kills the 94-MB pass-0.
//   s1_reduce: vsum = squash(0.1 * sum_rc part1) — contiguous 92 KB/b reads.
//   2x { caps_pass: NSPLIT=3, 768 blocks; FORCED 20-deep load burst via
//        explicit q0/q1 double-buffer + sched_barrier(0) (R8 showed VGPR=44:
//        compiler serializes bursts to ~4 in flight -> 2.6 TB/s wall);
//        caps_reduce: sum 3 partials + squash + vsum/out }
// Logits linear in v: b_t = u.(v1+..+v_{t-1}) -> running vsum, 1 pass/iter.
#define NB 256
#define NR 1152
#define NC 10
#define NI 8
#define NO 16
#define NSPLIT 3
#define NRC 144      // r-chunks in caps_u_s1 (8 r each)

static __device__ __forceinline__ uint32_t bf16_pack2(float lo, float hi) {
    uint32_t vl = __float_as_uint(lo);
    vl = vl + 0x7FFFu + ((vl >> 16) & 1u);
    uint32_t vh = __float_as_uint(hi);
    vh = vh + 0x7FFFu + ((vh >> 16) & 1u);
    return (vl >> 16) | (vh & 0xFFFF0000u);
}

// -------------------------------------------------------------------------
// caps_u_s1: R6-proven shape (2304 blocks = 144 rc x 16 bg; 320 thr =
// t = c*32 + rl*4 + oq; W[r][c][i][oq*4..+3] = 8 float4 in regs; b-loop 16).
// Adds: per-bi rl-shuffle-reduce (xor 4,8,16) of the fp32 u quad; rl==0
// lanes store float4 partial to part1[b][rc][c*16+oq*4] (row-contiguous).
__global__ __launch_bounds__(320, 2) void caps_u_s1_kernel(
    const float* __restrict__ x, const float* __restrict__ W,
    uint32_t* __restrict__ u, float* __restrict__ part1)
{
    const int t  = threadIdx.x;
    const int c  = t >> 5;             // 0..9
    const int rl = (t & 31) >> 2;      // 0..7
    const int oq = t & 3;              // 0..3
    const int rc = blockIdx.x >> 4;    // 0..143
    const int bg = blockIdx.x & 15;    // 0..15
    const int b0 = bg * 16;
    const int r  = rc * 8 + rl;

    __shared__ float xs[16][8][8];     // 4 KB

    if (t < 256) {                     // 256 float4 = x[b0..+16)[rc*8..+8)[8]
        const int bi = t >> 4, rem = t & 15;
        const int rr = rem >> 1, hf = rem & 1;
        *(float4*)&xs[bi][rr][hf * 4] =
            *(const float4*)(x + ((size_t)(b0 + bi) * NR + rc * 8 + rr) * 8 + hf * 4);
    }

    const float* wb = W + ((size_t)r * NC + c) * (NI * NO) + oq * 4;
    float4 wf[8];
#pragma unroll
    for (int i = 0; i < 8; ++i) wf[i] = *(const float4*)(wb + i * NO);

    __syncthreads();

    for (int bi = 0; bi < 16; ++bi) {
        const float4 xv4a = *(const float4*)&xs[bi][rl][0];
        const float4 xv4b = *(const float4*)&xs[bi][rl][4];
        const float xr[8] = {xv4a.x, xv4a.y, xv4a.z, xv4a.w,
                             xv4b.x, xv4b.y, xv4b.z, xv4b.w};
        float ax = 0.f, ay = 0.f, az = 0.f, aw = 0.f;
#pragma unroll
        for (int i = 0; i < 8; ++i) {
            const float xv = xr[i];
            ax = fmaf(xv, wf[i].x, ax); ay = fmaf(xv, wf[i].y, ay);
            az = fmaf(xv, wf[i].z, az); aw = fmaf(xv, wf[i].w, aw);
        }
        uint2 s;
        s.x = bf16_pack2(ax, ay);
        s.y = bf16_pack2(az, aw);
        *(uint2*)(u + (((size_t)(b0 + bi) * NC + c) * NR + r) * 8 + oq * 2) = s;

        // fused s1 partial: reduce fp32 quad over rl (lane bits 2..4)
        float sx = ax, sy = ay, sz = az, sw = aw;
#pragma unroll
        for (int off = 4; off <= 16; off <<= 1) {
            sx += __shfl_xor(sx, off); sy += __shfl_xor(sy, off);
            sz += __shfl_xor(sz, off); sw += __shfl_xor(sw, off);
        }
        if ((t & 28) == 0) {   // rl == 0 lanes: one float4 per (bi,c,oq)
            const float4 sv = {sx, sy, sz, sw};
            *(float4*)(part1 + (((size_t)(b0 + bi) * NRC + rc) * 160)
                       + c * 16 + oq * 4) = sv;
        }
    }
}

// -------------------------------------------------------------------------
// s1_reduce: vsum = squash(0.1 * sum over 144 rc). Contiguous 92 KB per b.
__global__ __launch_bounds__(192) void caps_s1_reduce_kernel(
    const float* __restrict__ part1, float* __restrict__ vsum)
{
    const int b = blockIdx.x;
    const int t = threadIdx.x;
    if (t >= 160) return;
    float s0 = 0.f, s1 = 0.f, s2 = 0.f, s3 = 0.f;
    const float* p = part1 + (size_t)b * NRC * 160 + t;
#pragma unroll 4
    for (int g = 0; g < NRC; g += 4) {
        s0 += p[(g + 0) * 160];
        s1 += p[(g + 1) * 160];
        s2 += p[(g + 2) * 160];
        s3 += p[(g + 3) * 160];
    }
    const float s = 0.1f * ((s0 + s1) + (s2 + s3));
    float n2 = s * s;
    n2 += __shfl_xor(n2, 1);
    n2 += __shfl_xor(n2, 2);
    n2 += __shfl_xor(n2, 4);
    n2 += __shfl_xor(n2, 8);
    const float nrm   = sqrtf(n2);
    const float scale = n2 / (1.f + n2) / (nrm + 1e-8f);
    vsum[(size_t)b * 160 + t] = scale * s;
}

// -------------------------------------------------------------------------
// one sweep of the routing pass: logits -> softmax -> weighted accumulate
static __device__ __forceinline__ void process_sweep(
    const uint4 q[10], const float* vss, const int oh, float acc[10][8])
{
    float lg[10];
#pragma unroll
    for (int c = 0; c < 10; ++c) {
        const float4 v0 = *(const float4*)&vss[c * 16 + oh * 8];
        const float4 v1 = *(const float4*)&vss[c * 16 + oh * 8 + 4];
        float d;
        d = __uint_as_float(q[c].x << 16)               * v0.x;
        d = fmaf(__uint_as_float(q[c].x & 0xFFFF0000u), v0.y, d);
        d = fmaf(__uint_as_float(q[c].y << 16),         v0.z, d);
        d = fmaf(__uint_as_float(q[c].y & 0xFFFF0000u), v0.w, d);
        d = fmaf(__uint_as_float(q[c].z << 16),         v1.x, d);
        d = fmaf(__uint_as_float(q[c].z & 0xFFFF0000u), v1.y, d);
        d = fmaf(__uint_as_float(q[c].w << 16),         v1.z, d);
        d = fmaf(__uint_as_float(q[c].w & 0xFFFF0000u), v1.w, d);
        lg[c] = d;
    }
#pragma unroll
    for (int c = 0; c < 10; ++c) lg[c] += __shfl_xor(lg[c], 1);  // join o-halves
    float m = lg[0];
#pragma unroll
    for (int c = 1; c < 10; ++c) m = fmaxf(m, lg[c]);
    float wgt[10], ssum = 0.f;
#pragma unroll
    for (int c = 0; c < 10; ++c) { wgt[c] = __expf(lg[c] - m); ssum += wgt[c]; }
    const float inv = 1.f / ssum;
#pragma unroll
    for (int c = 0; c < 10; ++c) {
        const float wv = wgt[c] * inv;
        acc[c][0] = fmaf(wv, __uint_as_float(q[c].x << 16),         acc[c][0]);
        acc[c][1] = fmaf(wv, __uint_as_float(q[c].x & 0xFFFF0000u), acc[c][1]);
        acc[c][2] = fmaf(wv, __uint_as_float(q[c].y << 16),         acc[c][2]);
        acc[c][3] = fmaf(wv, __uint_as_float(q[c].y & 0xFFFF0000u), acc[c][3]);
        acc[c][4] = fmaf(wv, __uint_as_float(q[c].z << 16),         acc[c][4]);
        acc[c][5] = fmaf(wv, __uint_as_float(q[c].z & 0xFFFF0000u), acc[c][5]);
        acc[c][6] = fmaf(wv, __uint_as_float(q[c].w << 16),         acc[c][6]);
        acc[c][7] = fmaf(wv, __uint_as_float(q[c].w & 0xFFFF0000u), acc[c][7]);
    }
}

// Routing pass: block=(b,sp), 256 thr = 128 rl x 2 oh; 3 sweeps of 128 r,
// q0/q1 staggered double-buffer (20 uint4 in flight), sched_barrier(0)
// pins the load groups. No launch_bounds min-waves: let VGPR grow ~210.
__global__ __launch_bounds__(256) void caps_pass_kernel(
    const uint32_t* __restrict__ u, const float* __restrict__ vsum,
    float* __restrict__ part2)
{
    const int b  = blockIdx.x / NSPLIT;
    const int sp = blockIdx.x % NSPLIT;
    const int t  = threadIdx.x;
    const int oh = t & 1;
    const int rl = t >> 1;    // 0..127

    __shared__ float vss[160];
    __shared__ float sred[32][164];

    if (t < 160) vss[t] = vsum[(size_t)b * 160 + t];
    __syncthreads();

    const uint4* ub = (const uint4*)u + (size_t)b * NC * NR * 2 + oh;
    const int r0 = sp * 384 + rl;

    uint4 q0[10], q1[10];
#pragma unroll
    for (int c = 0; c < 10; ++c) q0[c] = ub[((size_t)c * NR + r0) * 2];
#pragma unroll
    for (int c = 0; c < 10; ++c) q1[c] = ub[((size_t)c * NR + r0 + 128) * 2];
    __builtin_amdgcn_sched_barrier(0);   // 20 loads stay issued up-front

    float acc[10][8];
#pragma unroll
    for (int c = 0; c < 10; ++c)
#pragma unroll
        for (int j = 0; j < 8; ++j) acc[c][j] = 0.f;

    process_sweep(q0, vss, oh, acc);     // sweep 0
#pragma unroll
    for (int c = 0; c < 10; ++c) q0[c] = ub[((size_t)c * NR + r0 + 256) * 2];
    __builtin_amdgcn_sched_barrier(0);   // refill cannot sink below sweep 1
    process_sweep(q1, vss, oh, acc);     // sweep 1
    process_sweep(q0, vss, oh, acc);     // sweep 2

    // lean epilogue: reduce rl bits 0,1 in-wave (lane = rl*2+oh -> xor 2,4)
#pragma unroll
    for (int off = 2; off <= 4; off <<= 1)
#pragma unroll
        for (int c = 0; c < 10; ++c)
#pragma unroll
            for (int j = 0; j < 8; ++j) acc[c][j] += __shfl_xor(acc[c][j], off);

    const int lane = t & 63;
    const int wv   = t >> 6;
    if (((lane >> 1) & 3) == 0) {      // rl_local % 4 == 0: 16 lanes/wave
        const int g   = lane >> 3;     // 0..7
        const int row = wv * 8 + g;
#pragma unroll
        for (int c = 0; c < 10; ++c) {
            *(float4*)&sred[row][c * 16 + oh * 8]     = *(float4*)&acc[c][0];
            *(float4*)&sred[row][c * 16 + oh * 8 + 4] = *(float4*)&acc[c][4];
        }
    }
    __syncthreads();

    if (t < 160) {
        float s = 0.f;
#pragma unroll
        for (int w = 0; w < 32; ++w) s += sred[w][t];
        part2[((size_t)sp * NB + b) * 160 + t] = s;
    }
}

// -------------------------------------------------------------------------
// sum NSPLIT partials + squash. mode 1: vsum += v ; mode 2: out = v
__global__ __launch_bounds__(192) void caps_reduce_kernel(
    const float* __restrict__ part2, float* __restrict__ vsum,
    float* __restrict__ out, const int mode)
{
    const int b = blockIdx.x;
    const int t = threadIdx.x;
    if (t >= 160) return;
    float s = 0.f;
#pragma unroll
    for (int sp = 0; sp < NSPLIT; ++sp)
        s += part2[((size_t)sp * NB + b) * 160 + t];
    float n2 = s * s;
    n2 += __shfl_xor(n2, 1);
    n2 += __shfl_xor(n2, 2);
    n2 += __shfl_xor(n2, 4);
    n2 += __shfl_xor(n2, 8);
    const float nrm   = sqrtf(n2);
    const float scale = n2 / (1.f + n2) / (nrm + 1e-8f);
    const float v = scale * s;
    if (mode == 1) vsum[(size_t)b * 160 + t] += v;
    else           out[(size_t)b * 160 + t] = v;
}

// -------------------------------------------------------------------------
extern "C" void kernel_launch(void* const* d_in, const int* in_sizes, int n_in,
                              void* d_out, int out_size, void* d_ws, size_t ws_size,
                              hipStream_t stream) {
    const float* x = (const float*)d_in[0];   // [256,1152,8]
    const float* W = (const float*)d_in[1];   // [1,1152,10,8,16]
    float* out = (float*)d_out;               // [256,10,16]

    // ws: u 94,371,840 | part1 [256][144][160] = 23,592,960
    //     part2 3*256*160*4 = 491,520 | vsum 163,840
    uint8_t*  ws   = (uint8_t*)d_ws;
    uint32_t* u    = (uint32_t*)ws;
    float*    prt1 = (float*)(ws + 94371840u);
    float*    prt2 = (float*)(ws + 94371840u + 23592960u);
    float*    vsm  = (float*)(ws + 94371840u + 23592960u + 491520u);

    caps_u_s1_kernel     <<<2304, 320, 0, stream>>>(x, W, u, prt1);
    caps_s1_reduce_kernel<<<NB, 192, 0, stream>>>(prt1, vsm);
    caps_pass_kernel     <<<NB * NSPLIT, 256, 0, stream>>>(u, vsm, prt2);
    caps_reduce_kernel   <<<NB, 192, 0, stream>>>(prt2, vsm, nullptr, 1);
    caps_pass_kernel     <<<NB * NSPLIT, 256, 0, stream>>>(u, vsm, prt2);
    caps_reduce_kernel   <<<NB, 192, 0, stream>>>(prt2, nullptr, out, 2);
}

// Round 12
// 141.636 us; speedup vs baseline: 1.4108x; 1.1723x over previous
//
#include <hip/hip_runtime.h>
#include <cstdint>
#include <cstddef>

// DigitCapsules routing: B=256, R=1152, C=10, IC=8, OC=16, 3 iters.
// R12 (6 launches) = R11's fusion + R8's proven passes:
//   caps_u_s1: u bf16 (94 MB) + fused pass-0 partial (s1 needs no softmax;
//     12 shuffles/bi while u is in regs). bi-loop unroll-2 for ILP (the 44 us
//     = mem 23 + VALU 11 + DS 11 pipe-sum shows chains not overlapping).
//   s1_reduce: vsum = squash(0.1 * sum_rc part1), contiguous reads.
//   2x { caps_pass: R8's EXACT proven shape (NSPLIT=2, 9 sweeps of uint2,
//        launch_bounds(256,2), no sched_barrier) - 36 us measured;
//        caps_reduce: squash + vsum/out }
// Logits linear in v: b_t = u.(v1+..+v_{t-1}) -> running vsum, 1 pass/iter.
// R9/R11 lesson: do NOT out-schedule the compiler (sched_barrier/min-waves
// caps both regressed); R2/R4/R5 lesson: never exceed the VGPR budget.
#define NB 256
#define NR 1152
#define NC 10
#define NI 8
#define NO 16
#define NSPLIT 2
#define NSWEEP 9     // r-sweeps per pass thread: 9*64 = 576 = NR/NSPLIT
#define NRC 144      // r-chunks in caps_u_s1 (8 r each)

static __device__ __forceinline__ uint32_t bf16_pack2(float lo, float hi) {
    uint32_t vl = __float_as_uint(lo);
    vl = vl + 0x7FFFu + ((vl >> 16) & 1u);
    uint32_t vh = __float_as_uint(hi);
    vh = vh + 0x7FFFu + ((vh >> 16) & 1u);
    return (vl >> 16) | (vh & 0xFFFF0000u);
}

// -------------------------------------------------------------------------
// caps_u_s1: 2304 blocks = 144 rc x 16 bg; 320 thr = c*32 + rl*4 + oq.
// W[r][c][i][oq*4..+3] = 8 float4 in regs; 16-deep b-loop (unroll 2).
// Per bi: u quad -> bf16 store + rl-shuffle-reduce (xor 4,8,16) -> rl==0
// lanes store fp32 float4 partial to part1[b][rc][c*16+oq*4].
__global__ __launch_bounds__(320, 2) void caps_u_s1_kernel(
    const float* __restrict__ x, const float* __restrict__ W,
    uint32_t* __restrict__ u, float* __restrict__ part1)
{
    const int t  = threadIdx.x;
    const int c  = t >> 5;             // 0..9
    const int rl = (t & 31) >> 2;      // 0..7
    const int oq = t & 3;              // 0..3
    const int rc = blockIdx.x >> 4;    // 0..143
    const int bg = blockIdx.x & 15;    // 0..15
    const int b0 = bg * 16;
    const int r  = rc * 8 + rl;

    __shared__ float xs[16][8][8];     // 4 KB

    if (t < 256) {                     // 256 float4 = x[b0..+16)[rc*8..+8)[8]
        const int bi = t >> 4, rem = t & 15;
        const int rr = rem >> 1, hf = rem & 1;
        *(float4*)&xs[bi][rr][hf * 4] =
            *(const float4*)(x + ((size_t)(b0 + bi) * NR + rc * 8 + rr) * 8 + hf * 4);
    }

    const float* wb = W + ((size_t)r * NC + c) * (NI * NO) + oq * 4;
    float4 wf[8];
#pragma unroll
    for (int i = 0; i < 8; ++i) wf[i] = *(const float4*)(wb + i * NO);

    __syncthreads();

#pragma unroll 2
    for (int bi = 0; bi < 16; ++bi) {
        const float4 xv4a = *(const float4*)&xs[bi][rl][0];
        const float4 xv4b = *(const float4*)&xs[bi][rl][4];
        const float xr[8] = {xv4a.x, xv4a.y, xv4a.z, xv4a.w,
                             xv4b.x, xv4b.y, xv4b.z, xv4b.w};
        float ax = 0.f, ay = 0.f, az = 0.f, aw = 0.f;
#pragma unroll
        for (int i = 0; i < 8; ++i) {
            const float xv = xr[i];
            ax = fmaf(xv, wf[i].x, ax); ay = fmaf(xv, wf[i].y, ay);
            az = fmaf(xv, wf[i].z, az); aw = fmaf(xv, wf[i].w, aw);
        }
        uint2 s;
        s.x = bf16_pack2(ax, ay);
        s.y = bf16_pack2(az, aw);
        *(uint2*)(u + (((size_t)(b0 + bi) * NC + c) * NR + r) * 8 + oq * 2) = s;

        // fused s1 partial: reduce fp32 quad over rl (lane bits 2..4)
        float sx = ax, sy = ay, sz = az, sw = aw;
#pragma unroll
        for (int off = 4; off <= 16; off <<= 1) {
            sx += __shfl_xor(sx, off); sy += __shfl_xor(sy, off);
            sz += __shfl_xor(sz, off); sw += __shfl_xor(sw, off);
        }
        if ((t & 28) == 0) {   // rl == 0 lanes: one float4 per (bi,c,oq)
            const float4 sv = {sx, sy, sz, sw};
            *(float4*)(part1 + (((size_t)(b0 + bi) * NRC + rc) * 160)
                       + c * 16 + oq * 4) = sv;
        }
    }
}

// -------------------------------------------------------------------------
// s1_reduce: vsum = squash(0.1 * sum over 144 rc). Contiguous 92 KB per b.
__global__ __launch_bounds__(192) void caps_s1_reduce_kernel(
    const float* __restrict__ part1, float* __restrict__ vsum)
{
    const int b = blockIdx.x;
    const int t = threadIdx.x;
    if (t >= 160) return;
    float s0 = 0.f, s1 = 0.f, s2 = 0.f, s3 = 0.f;
    const float* p = part1 + (size_t)b * NRC * 160 + t;
#pragma unroll 4
    for (int g = 0; g < NRC; g += 4) {
        s0 += p[(g + 0) * 160];
        s1 += p[(g + 1) * 160];
        s2 += p[(g + 2) * 160];
        s3 += p[(g + 3) * 160];
    }
    const float s = 0.1f * ((s0 + s1) + (s2 + s3));
    float n2 = s * s;
    n2 += __shfl_xor(n2, 1);
    n2 += __shfl_xor(n2, 2);
    n2 += __shfl_xor(n2, 4);
    n2 += __shfl_xor(n2, 8);
    const float nrm   = sqrtf(n2);
    const float scale = n2 / (1.f + n2) / (nrm + 1e-8f);
    vsum[(size_t)b * 160 + t] = scale * s;
}

// -------------------------------------------------------------------------
// Routing pass (R8's exact proven shape): block = (b, sp), 256 thr =
// 64 rl x 4 oq, NSWEEP=9 sweeps of uint2 loads. cc = softmax_c(u.vsum).
// Partial s -> part2[sp][b][160]. No atomics.
__global__ __launch_bounds__(256, 2) void caps_pass_kernel(
    const uint32_t* __restrict__ u, const float* __restrict__ vsum,
    float* __restrict__ part2)
{
    const int b  = blockIdx.x >> 1;
    const int sp = blockIdx.x & 1;
    const int t  = threadIdx.x;
    const int oq = t & 3;
    const int rl = t >> 2;    // 0..63

    __shared__ float vss[160];
    __shared__ float sred[4][160];

    if (t < 160) vss[t] = vsum[(size_t)b * 160 + t];
    __syncthreads();

    float acc[10][4];
#pragma unroll
    for (int c = 0; c < 10; ++c)
#pragma unroll
        for (int j = 0; j < 4; ++j) acc[c][j] = 0.f;

    const uint2* ub = (const uint2*)u + (size_t)b * NC * NR * 4 + oq;

    for (int k = 0; k < NSWEEP; ++k) {
        const int r = sp * (NSWEEP * 64) + k * 64 + rl;
        uint2 q[10];
#pragma unroll
        for (int c = 0; c < 10; ++c) q[c] = ub[((size_t)c * NR + r) * 4];

        float lg[10];
#pragma unroll
        for (int c = 0; c < 10; ++c) {
            const float4 vq = *(const float4*)&vss[c * 16 + oq * 4];
            float d = __uint_as_float(q[c].x << 16) * vq.x;
            d = fmaf(__uint_as_float(q[c].x & 0xFFFF0000u), vq.y, d);
            d = fmaf(__uint_as_float(q[c].y << 16),         vq.z, d);
            d = fmaf(__uint_as_float(q[c].y & 0xFFFF0000u), vq.w, d);
            lg[c] = d;
        }
#pragma unroll
        for (int c = 0; c < 10; ++c) {    // finish o-dot over 4 oq lanes
            lg[c] += __shfl_xor(lg[c], 1);
            lg[c] += __shfl_xor(lg[c], 2);
        }
        float m = lg[0];
#pragma unroll
        for (int c = 1; c < 10; ++c) m = fmaxf(m, lg[c]);
        float wgt[10], ssum = 0.f;
#pragma unroll
        for (int c = 0; c < 10; ++c) { wgt[c] = __expf(lg[c] - m); ssum += wgt[c]; }
        const float inv = 1.f / ssum;
#pragma unroll
        for (int c = 0; c < 10; ++c) {
            const float wv = wgt[c] * inv;
            acc[c][0] = fmaf(wv, __uint_as_float(q[c].x << 16),         acc[c][0]);
            acc[c][1] = fmaf(wv, __uint_as_float(q[c].x & 0xFFFF0000u), acc[c][1]);
            acc[c][2] = fmaf(wv, __uint_as_float(q[c].y << 16),         acc[c][2]);
            acc[c][3] = fmaf(wv, __uint_as_float(q[c].y & 0xFFFF0000u), acc[c][3]);
        }
    }

    // in-wave reduce over 16 rl-lanes (tid bits 2..5) — once per 9 r
#pragma unroll
    for (int off = 4; off <= 32; off <<= 1)
#pragma unroll
        for (int c = 0; c < 10; ++c)
#pragma unroll
            for (int j = 0; j < 4; ++j) acc[c][j] += __shfl_xor(acc[c][j], off);

    const int wv = t >> 6;
    if ((t & 63) < 4) {
#pragma unroll
        for (int c = 0; c < 10; ++c)
#pragma unroll
            for (int j = 0; j < 4; ++j)
                sred[wv][c * 16 + oq * 4 + j] = acc[c][j];
    }
    __syncthreads();

    if (t < 160) {
        part2[((size_t)sp * NB + b) * 160 + t]
            = sred[0][t] + sred[1][t] + sred[2][t] + sred[3][t];
    }
}

// -------------------------------------------------------------------------
// sum NSPLIT partials + squash. mode 1: vsum += v ; mode 2: out = v
__global__ __launch_bounds__(192) void caps_reduce_kernel(
    const float* __restrict__ part2, float* __restrict__ vsum,
    float* __restrict__ out, const int mode)
{
    const int b = blockIdx.x;
    const int t = threadIdx.x;
    if (t >= 160) return;
    float s = 0.f;
#pragma unroll
    for (int sp = 0; sp < NSPLIT; ++sp)
        s += part2[((size_t)sp * NB + b) * 160 + t];
    float n2 = s * s;
    n2 += __shfl_xor(n2, 1);
    n2 += __shfl_xor(n2, 2);
    n2 += __shfl_xor(n2, 4);
    n2 += __shfl_xor(n2, 8);
    const float nrm   = sqrtf(n2);
    const float scale = n2 / (1.f + n2) / (nrm + 1e-8f);
    const float v = scale * s;
    if (mode == 1) vsum[(size_t)b * 160 + t] += v;
    else           out[(size_t)b * 160 + t] = v;
}

// -------------------------------------------------------------------------
extern "C" void kernel_launch(void* const* d_in, const int* in_sizes, int n_in,
                              void* d_out, int out_size, void* d_ws, size_t ws_size,
                              hipStream_t stream) {
    const float* x = (const float*)d_in[0];   // [256,1152,8]
    const float* W = (const float*)d_in[1];   // [1,1152,10,8,16]
    float* out = (float*)d_out;               // [256,10,16]

    // ws: u 94,371,840 | part1 [256][144][160] = 23,592,960
    //     part2 2*256*160*4 = 327,680 | vsum 163,840
    uint8_t*  ws   = (uint8_t*)d_ws;
    uint32_t* u    = (uint32_t*)ws;
    float*    prt1 = (float*)(ws + 94371840u);
    float*    prt2 = (float*)(ws + 94371840u + 23592960u);
    float*    vsm  = (float*)(ws + 94371840u + 23592960u + 327680u);

    caps_u_s1_kernel     <<<2304, 320, 0, stream>>>(x, W, u, prt1);
    caps_s1_reduce_kernel<<<NB, 192, 0, stream>>>(prt1, vsm);
    caps_pass_kernel     <<<NB * NSPLIT, 256, 0, stream>>>(u, vsm, prt2);
    caps_reduce_kernel   <<<NB, 192, 0, stream>>>(prt2, vsm, nullptr, 1);
    caps_pass_kernel     <<<NB * NSPLIT, 256, 0, stream>>>(u, vsm, prt2);
    caps_reduce_kernel   <<<NB, 192, 0, stream>>>(prt2, nullptr, out, 2);
}